// Round 1
// baseline (680.215 us; speedup 1.0000x reference)
//
#include <hip/hip_runtime.h>

// Analysis filters
__device__ __constant__ float H0[8] = { 0.0322231f, -0.01260397f, -0.09921954f,  0.2978578f,
                                        0.80373875f, 0.49761867f, -0.02963553f, -0.07576571f};
__device__ __constant__ float H1[8] = { 0.07576571f, -0.02963553f, -0.49761867f, 0.80373875f,
                                       -0.2978578f, -0.09921954f,  0.01260397f,  0.0322231f};
// Synthesis filters g0 = reverse(h0), g1 = reverse(h1)
__device__ __constant__ float G0[8] = {-0.07576571f, -0.02963553f,  0.49761867f, 0.80373875f,
                                        0.2978578f,  -0.09921954f, -0.01260397f, 0.0322231f};
__device__ __constant__ float G1[8] = { 0.0322231f,   0.01260397f, -0.09921954f, -0.2978578f,
                                        0.80373875f, -0.49761867f, -0.02963553f, 0.07576571f};

// ---------------------------------------------------------------------------
// Forward DWT: stride-2 depthwise conv with 4 separable 8x8 kernels.
// SAME pad for stride2/k8: lo=3. out[oh,ow] = sum_{u,v} in[2oh+u-3, 2ow+v-3]*ka[u]*kb[v]
// Lane = channel (64) -> every load is a 256B coalesced wave transaction.
// ---------------------------------------------------------------------------
template<int HIN>
__global__ __launch_bounds__(256) void fwd_dwt(const float* __restrict__ in,
                                               float* __restrict__ oLL, float* __restrict__ oLH,
                                               float* __restrict__ oHL, float* __restrict__ oHH)
{
    constexpr int OH = HIN / 2;
    const int tid = threadIdx.x;
    const int c = tid & 63;
    const int s = blockIdx.x * 4 + (tid >> 6);
    const int ow = s % OH;
    const int oh = (s / OH) % OH;
    const int b  = s / (OH * OH);

    float aLL = 0.f, aLH = 0.f, aHL = 0.f, aHH = 0.f;
#pragma unroll
    for (int u = 0; u < 8; ++u) {
        const int ih = 2 * oh + u - 3;
        if ((unsigned)ih < (unsigned)HIN) {
            const float* row = in + ((b * HIN + ih) * HIN) * 64 + c;
            float s0 = 0.f, s1 = 0.f;
#pragma unroll
            for (int v = 0; v < 8; ++v) {
                const int iw = 2 * ow + v - 3;
                if ((unsigned)iw < (unsigned)HIN) {
                    const float xv = row[iw * 64];
                    s0 += xv * H0[v];
                    s1 += xv * H1[v];
                }
            }
            aLL += H0[u] * s0;
            aLH += H0[u] * s1;
            aHL += H1[u] * s0;
            aHH += H1[u] * s1;
        }
    }
    const int oidx = ((b * OH + oh) * OH + ow) * 64 + c;
    oLL[oidx] = aLL; oLH[oidx] = aLH; oHL[oidx] = aHL; oHH[oidx] = aHH;
}

// ---------------------------------------------------------------------------
// Local conv: out[b,h,w,o] = sum_i t[b,h,w,i] * W[i,o,w,h]   (W: [C][O][Wd][Hd], h innermost)
// Weights are only contiguous in h -> lanes = h so each weight element is
// loaded exactly once from HBM, coalesced. Block = (w, o-group of 16), all b.
// BJ = HD/16 batches per thread, acc[BJ][16] in registers.
// ---------------------------------------------------------------------------
template<int HD, int BJ>
__global__ __launch_bounds__(256) void local_conv(
    const float* __restrict__ t0, const float* __restrict__ t1,
    const float* __restrict__ t2, const float* __restrict__ t3,
    const float* __restrict__ w0, const float* __restrict__ w1,
    const float* __restrict__ w2, const float* __restrict__ w3,
    float* __restrict__ o0, float* __restrict__ o1,
    float* __restrict__ o2, float* __restrict__ o3)
{
    const int z = blockIdx.z;
    const float* tin = (z == 0) ? t0 : (z == 1) ? t1 : (z == 2) ? t2 : t3;
    const float* wgt = (z == 0) ? w0 : (z == 1) ? w1 : (z == 2) ? w2 : w3;
    float*       out = (z == 0) ? o0 : (z == 1) ? o1 : (z == 2) ? o2 : o3;

    const int w   = blockIdx.x;
    const int og  = blockIdx.y;          // o-group of 16
    const int tid = threadIdx.x;
    const int h   = tid % HD;
    const int bg  = tid / HD;            // 256/HD groups of BJ batches
    constexpr int WH = HD * HD;

    float acc[BJ][16];
#pragma unroll
    for (int j = 0; j < BJ; ++j)
#pragma unroll
        for (int oo = 0; oo < 16; ++oo) acc[j][oo] = 0.f;

    for (int i4 = 0; i4 < 16; ++i4) {
        float4 tv[BJ];
#pragma unroll
        for (int j = 0; j < BJ; ++j) {
            const int b = bg * BJ + j;
            tv[j] = *(const float4*)(tin + ((b * HD + h) * HD + w) * 64 + i4 * 4);
        }
#pragma unroll
        for (int di = 0; di < 4; ++di) {
            const int i = i4 * 4 + di;
            const float* wp = wgt + (i * 64 + og * 16) * WH + w * HD + h;
#pragma unroll
            for (int oo = 0; oo < 16; ++oo) {
                const float wv = wp[oo * WH];
#pragma unroll
                for (int j = 0; j < BJ; ++j) {
                    const float tj = ((const float*)&tv[j])[di];
                    acc[j][oo] += tj * wv;
                }
            }
        }
    }

#pragma unroll
    for (int j = 0; j < BJ; ++j) {
        const int b = bg * BJ + j;
        float* op = out + ((b * HD + h) * HD + w) * 64 + og * 16;
#pragma unroll
        for (int o4 = 0; o4 < 4; ++o4) {
            float4 v = make_float4(acc[j][o4 * 4 + 0], acc[j][o4 * 4 + 1],
                                   acc[j][o4 * 4 + 2], acc[j][o4 * 4 + 3]);
            *(float4*)(op + o4 * 4) = v;
        }
    }
}

// ---------------------------------------------------------------------------
// Inverse DWT level: r = sum of 4 upsample+conv (stride1, SAME pad lo=3).
// up[2m]=y[m]; h+u-3 must be even -> u parity p=(h+1)&1, 4 taps per axis.
// out[h,w] = sum_{ku,kv} a(u)*b(v)*y[mbase+ku, nbase+kv]
// ---------------------------------------------------------------------------
template<int HOUT>
__global__ __launch_bounds__(256) void inv_dwt(const float* __restrict__ yLL,
                                               const float* __restrict__ yLH,
                                               const float* __restrict__ yHL,
                                               const float* __restrict__ yHH,
                                               float* __restrict__ out)
{
    constexpr int HS = HOUT / 2;
    const int tid = threadIdx.x;
    const int c = tid & 63;
    const int s = blockIdx.x * 4 + (tid >> 6);
    const int w = s % HOUT;
    const int h = (s / HOUT) % HOUT;
    const int b = s / (HOUT * HOUT);

    const int ph = (h + 1) & 1;
    const int pw = (w + 1) & 1;
    const int mbase = (h - 3 + ph) >> 1;   // arithmetic shift ok (value is even)
    const int nbase = (w - 3 + pw) >> 1;

    float acc = 0.f;
#pragma unroll
    for (int ku = 0; ku < 4; ++ku) {
        const int m = mbase + ku;
        if ((unsigned)m < (unsigned)HS) {
            const float a0 = G0[ph + 2 * ku];
            const float a1 = G1[ph + 2 * ku];
            const int rowoff = (b * HS + m) * HS;
#pragma unroll
            for (int kv = 0; kv < 4; ++kv) {
                const int n = nbase + kv;
                if ((unsigned)n < (unsigned)HS) {
                    const float b0 = G0[pw + 2 * kv];
                    const float b1 = G1[pw + 2 * kv];
                    const int idx = (rowoff + n) * 64 + c;
                    acc += a0 * (b0 * yLL[idx] + b1 * yLH[idx])
                         + a1 * (b0 * yHL[idx] + b1 * yHH[idx]);
                }
            }
        }
    }
    out[((b * HOUT + h) * HOUT + w) * 64 + c] = acc;
}

// ---------------------------------------------------------------------------
extern "C" void kernel_launch(void* const* d_in, const int* in_sizes, int n_in,
                              void* d_out, int out_size, void* d_ws, size_t ws_size,
                              hipStream_t stream)
{
    const float* x    = (const float*)d_in[0];
    const float* wLL  = (const float*)d_in[1];
    const float* wLH0 = (const float*)d_in[2];
    const float* wHL0 = (const float*)d_in[3];
    const float* wHH0 = (const float*)d_in[4];
    const float* wLH1 = (const float*)d_in[5];
    const float* wHL1 = (const float*)d_in[6];
    const float* wHH1 = (const float*)d_in[7];
    float* out = (float*)d_out;
    float* ws  = (float*)d_ws;

    const int S0 = 16 * 64 * 64 * 64;   // 4,194,304  (level-0 subband elems)
    const int S1 = 16 * 32 * 32 * 64;   // 1,048,576  (level-1 subband elems)

    // d_out doubles as scratch for the 4 level-0 subbands (fills it exactly);
    // it is fully overwritten by the final inverse level.
    float* c0LL = out;
    float* c0LH = out + 1 * S0;
    float* c0HL = out + 2 * S0;
    float* c0HH = out + 3 * S0;

    // ws layout (20,971,520 floats = 84 MB):
    float* c1   = ws;                      // 4*S1 (LL,LH,HL,HH) -> later reused as r1
    float* t0   = ws + 4 * S1;             // 3*S0
    float* t1   = ws + 4 * S1 + 3 * S0;    // 3*S1
    float* yA   = ws + 7 * S1 + 3 * S0;    // S1
    float* r1   = ws;                      // S0 == 4*S1, overwrites dead c1

    // 1) level-0 forward DWT: x (16,128,128,64) -> 4x (16,64,64,64)
    fwd_dwt<128><<<16 * 64 * 64 / 4, 256, 0, stream>>>(x, c0LL, c0LH, c0HL, c0HH);

    // 2) level-1 forward DWT: cLL0 -> 4x (16,32,32,64)
    fwd_dwt<64><<<16 * 32 * 32 / 4, 256, 0, stream>>>(c0LL,
        c1 + 0 * S1, c1 + 1 * S1, c1 + 2 * S1, c1 + 3 * S1);

    // 3) local conv level-0 details (Hd=Wd=64): 3 tensors
    local_conv<64, 4><<<dim3(64, 4, 3), 256, 0, stream>>>(
        c0LH, c0HL, c0HH, nullptr,
        wLH0, wHL0, wHH0, nullptr,
        t0 + 0 * S0, t0 + 1 * S0, t0 + 2 * S0, nullptr);

    // 4) local conv level-1 (Hd=Wd=32): LH,HL,HH details + LL (yA)
    local_conv<32, 2><<<dim3(32, 4, 4), 256, 0, stream>>>(
        c1 + 1 * S1, c1 + 2 * S1, c1 + 3 * S1, c1 + 0 * S1,
        wLH1, wHL1, wHH1, wLL,
        t1 + 0 * S1, t1 + 1 * S1, t1 + 2 * S1, yA);

    // 5) inverse level-1: (yA, t1) -> r1 (16,64,64,64)
    inv_dwt<64><<<16 * 64 * 64 / 4, 256, 0, stream>>>(
        yA, t1 + 0 * S1, t1 + 1 * S1, t1 + 2 * S1, r1);

    // 6) inverse level-0: (r1, t0) -> out (16,128,128,64)
    inv_dwt<128><<<16 * 128 * 128 / 4, 256, 0, stream>>>(
        r1, t0 + 0 * S0, t0 + 1 * S0, t0 + 2 * S0, out);
}

// Round 2
// 335.175 us; speedup vs baseline: 2.0294x; 2.0294x over previous
//
#include <hip/hip_runtime.h>

// Analysis filters
__device__ __constant__ float H0[8] = { 0.0322231f, -0.01260397f, -0.09921954f,  0.2978578f,
                                        0.80373875f, 0.49761867f, -0.02963553f, -0.07576571f};
__device__ __constant__ float H1[8] = { 0.07576571f, -0.02963553f, -0.49761867f, 0.80373875f,
                                       -0.2978578f, -0.09921954f,  0.01260397f,  0.0322231f};
// Synthesis filters g0 = reverse(h0), g1 = reverse(h1)
__device__ __constant__ float G0[8] = {-0.07576571f, -0.02963553f,  0.49761867f, 0.80373875f,
                                        0.2978578f,  -0.09921954f, -0.01260397f, 0.0322231f};
__device__ __constant__ float G1[8] = { 0.0322231f,   0.01260397f, -0.09921954f, -0.2978578f,
                                        0.80373875f, -0.49761867f, -0.02963553f, 0.07576571f};

// ---------------------------------------------------------------------------
// Forward DWT, 2x2-output-tiled + separable.
// Each thread computes outputs (2i..2i+1)x(2j..2j+1) for one channel c.
// Input patch: rows 4i-3..4i+6, cols 4j-3..4j+6 (10x10) -> 100 loads / 4 outputs.
// ---------------------------------------------------------------------------
template<int HIN>
__global__ __launch_bounds__(256) void fwd_dwt(const float* __restrict__ in,
                                               float* __restrict__ oLL, float* __restrict__ oLH,
                                               float* __restrict__ oHL, float* __restrict__ oHH)
{
    constexpr int OH = HIN / 2;
    constexpr int TQ = OH / 2;
    const int tid = threadIdx.x;
    const int c = tid & 63;
    const int s = blockIdx.x * 4 + (tid >> 6);
    const int j = s % TQ;
    const int i = (s / TQ) % TQ;
    const int b = s / (TQ * TQ);

    float acc[2][2][4];
#pragma unroll
    for (int a = 0; a < 2; ++a)
#pragma unroll
        for (int d = 0; d < 2; ++d)
#pragma unroll
            for (int k = 0; k < 4; ++k) acc[a][d][k] = 0.f;

    const int iw0 = 4 * j - 3;
#pragma unroll
    for (int r = 0; r < 10; ++r) {
        const int ih = 4 * i + r - 3;
        if ((unsigned)ih < (unsigned)HIN) {
            const float* row = in + ((b * HIN + ih) * HIN) * 64 + c;
            float xv[10];
#pragma unroll
            for (int v = 0; v < 10; ++v) {
                const int iw = iw0 + v;
                xv[v] = ((unsigned)iw < (unsigned)HIN) ? row[iw * 64] : 0.f;
            }
            // horizontal pass: filters H0/H1 at the two ow positions
            float h00 = 0.f, h01 = 0.f, h10 = 0.f, h11 = 0.f;
#pragma unroll
            for (int v = 0; v < 8; ++v) {
                h00 += H0[v] * xv[v];
                h10 += H1[v] * xv[v];
                h01 += H0[v] * xv[v + 2];
                h11 += H1[v] * xv[v + 2];
            }
            // vertical accumulate into the valid output rows
#pragma unroll
            for (int ii = 0; ii < 2; ++ii) {
                const int u = r - 2 * ii;
                if (0 <= u && u < 8) {
                    const float a0 = H0[u], a1 = H1[u];
                    acc[ii][0][0] += a0 * h00;  // LL
                    acc[ii][0][1] += a0 * h10;  // LH (horiz H1)
                    acc[ii][0][2] += a1 * h00;  // HL
                    acc[ii][0][3] += a1 * h10;  // HH
                    acc[ii][1][0] += a0 * h01;
                    acc[ii][1][1] += a0 * h11;
                    acc[ii][1][2] += a1 * h01;
                    acc[ii][1][3] += a1 * h11;
                }
            }
        }
    }

#pragma unroll
    for (int ii = 0; ii < 2; ++ii)
#pragma unroll
        for (int jj = 0; jj < 2; ++jj) {
            const int oh = 2 * i + ii, ow = 2 * j + jj;
            const int oidx = ((b * OH + oh) * OH + ow) * 64 + c;
            oLL[oidx] = acc[ii][jj][0];
            oLH[oidx] = acc[ii][jj][1];
            oHL[oidx] = acc[ii][jj][2];
            oHH[oidx] = acc[ii][jj][3];
        }
}

// ---------------------------------------------------------------------------
// Local conv: out[b,h,w,o] = sum_i t[b,h,w,i] * W[i,o,w,h]   (W: [C][O][Wd][Hd], h innermost)
// ---------------------------------------------------------------------------
template<int HD, int BJ>
__global__ __launch_bounds__(256) void local_conv(
    const float* __restrict__ t0, const float* __restrict__ t1,
    const float* __restrict__ t2, const float* __restrict__ t3,
    const float* __restrict__ w0, const float* __restrict__ w1,
    const float* __restrict__ w2, const float* __restrict__ w3,
    float* __restrict__ o0, float* __restrict__ o1,
    float* __restrict__ o2, float* __restrict__ o3)
{
    const int z = blockIdx.z;
    const float* tin = (z == 0) ? t0 : (z == 1) ? t1 : (z == 2) ? t2 : t3;
    const float* wgt = (z == 0) ? w0 : (z == 1) ? w1 : (z == 2) ? w2 : w3;
    float*       out = (z == 0) ? o0 : (z == 1) ? o1 : (z == 2) ? o2 : o3;

    const int w   = blockIdx.x;
    const int og  = blockIdx.y;          // o-group of 16
    const int tid = threadIdx.x;
    const int h   = tid % HD;
    const int bg  = tid / HD;            // 256/HD groups of BJ batches
    constexpr int WH = HD * HD;

    float acc[BJ][16];
#pragma unroll
    for (int j = 0; j < BJ; ++j)
#pragma unroll
        for (int oo = 0; oo < 16; ++oo) acc[j][oo] = 0.f;

    for (int i4 = 0; i4 < 16; ++i4) {
        float4 tv[BJ];
#pragma unroll
        for (int j = 0; j < BJ; ++j) {
            const int b = bg * BJ + j;
            tv[j] = *(const float4*)(tin + ((b * HD + h) * HD + w) * 64 + i4 * 4);
        }
#pragma unroll
        for (int di = 0; di < 4; ++di) {
            const int i = i4 * 4 + di;
            const float* wp = wgt + (i * 64 + og * 16) * WH + w * HD + h;
#pragma unroll
            for (int oo = 0; oo < 16; ++oo) {
                const float wv = wp[oo * WH];
#pragma unroll
                for (int j = 0; j < BJ; ++j) {
                    const float tj = ((const float*)&tv[j])[di];
                    acc[j][oo] += tj * wv;
                }
            }
        }
    }

#pragma unroll
    for (int j = 0; j < BJ; ++j) {
        const int b = bg * BJ + j;
        float* op = out + ((b * HD + h) * HD + w) * 64 + og * 16;
#pragma unroll
        for (int o4 = 0; o4 < 4; ++o4) {
            float4 v = make_float4(acc[j][o4 * 4 + 0], acc[j][o4 * 4 + 1],
                                   acc[j][o4 * 4 + 2], acc[j][o4 * 4 + 3]);
            *(float4*)(op + o4 * 4) = v;
        }
    }
}

// ---------------------------------------------------------------------------
// Inverse DWT, 2x2-output-tiled + separable.
// Outputs (2i,2i+1)x(2j,2j+1) share the y-window m in i-1..i+2, n in j-1..j+2.
// Column pass accumulates P (horiz G0 group: LL,HL) and Q (horiz G1: LH,HH)
// for even/odd output rows, then a 4-tap row pass produces the 4 outputs.
// ---------------------------------------------------------------------------
template<int HOUT>
__global__ __launch_bounds__(256) void inv_dwt(const float* __restrict__ yLL,
                                               const float* __restrict__ yLH,
                                               const float* __restrict__ yHL,
                                               const float* __restrict__ yHH,
                                               float* __restrict__ out)
{
    constexpr int HS = HOUT / 2;
    const int tid = threadIdx.x;
    const int c = tid & 63;
    const int s = blockIdx.x * 4 + (tid >> 6);
    const int j = s % HS;
    const int i = (s / HS) % HS;
    const int b = s / (HS * HS);

    float Pe[4] = {0.f, 0.f, 0.f, 0.f}, Po[4] = {0.f, 0.f, 0.f, 0.f};
    float Qe[4] = {0.f, 0.f, 0.f, 0.f}, Qo[4] = {0.f, 0.f, 0.f, 0.f};

#pragma unroll
    for (int ku = 0; ku < 4; ++ku) {
        const int m = i - 1 + ku;
        if ((unsigned)m < (unsigned)HS) {
            const float a0e = G0[1 + 2 * ku], a0o = G0[2 * ku];
            const float a1e = G1[1 + 2 * ku], a1o = G1[2 * ku];
            const int rowoff = (b * HS + m) * HS;
#pragma unroll
            for (int kv = 0; kv < 4; ++kv) {
                const int n = j - 1 + kv;
                if ((unsigned)n < (unsigned)HS) {
                    const int idx = (rowoff + n) * 64 + c;
                    const float yll = yLL[idx], ylh = yLH[idx];
                    const float yhl = yHL[idx], yhh = yHH[idx];
                    Pe[kv] += a0e * yll + a1e * yhl;
                    Po[kv] += a0o * yll + a1o * yhl;
                    Qe[kv] += a0e * ylh + a1e * yhh;
                    Qo[kv] += a0o * ylh + a1o * yhh;
                }
            }
        }
    }

    float o00 = 0.f, o01 = 0.f, o10 = 0.f, o11 = 0.f;
#pragma unroll
    for (int kv = 0; kv < 4; ++kv) {
        const float b0e = G0[1 + 2 * kv], b0o = G0[2 * kv];
        const float b1e = G1[1 + 2 * kv], b1o = G1[2 * kv];
        o00 += b0e * Pe[kv] + b1e * Qe[kv];
        o01 += b0o * Pe[kv] + b1o * Qe[kv];
        o10 += b0e * Po[kv] + b1e * Qo[kv];
        o11 += b0o * Po[kv] + b1o * Qo[kv];
    }

    const int h0 = 2 * i, w0 = 2 * j;
    const int base = ((b * HOUT + h0) * HOUT + w0) * 64 + c;
    out[base] = o00;
    out[base + 64] = o01;
    out[base + HOUT * 64] = o10;
    out[base + HOUT * 64 + 64] = o11;
}

// ---------------------------------------------------------------------------
extern "C" void kernel_launch(void* const* d_in, const int* in_sizes, int n_in,
                              void* d_out, int out_size, void* d_ws, size_t ws_size,
                              hipStream_t stream)
{
    const float* x    = (const float*)d_in[0];
    const float* wLL  = (const float*)d_in[1];
    const float* wLH0 = (const float*)d_in[2];
    const float* wHL0 = (const float*)d_in[3];
    const float* wHH0 = (const float*)d_in[4];
    const float* wLH1 = (const float*)d_in[5];
    const float* wHL1 = (const float*)d_in[6];
    const float* wHH1 = (const float*)d_in[7];
    float* out = (float*)d_out;
    float* ws  = (float*)d_ws;

    const int S0 = 16 * 64 * 64 * 64;   // level-0 subband elems
    const int S1 = 16 * 32 * 32 * 64;   // level-1 subband elems

    // d_out doubles as scratch for the 4 level-0 subbands.
    float* c0LL = out;
    float* c0LH = out + 1 * S0;
    float* c0HL = out + 2 * S0;
    float* c0HH = out + 3 * S0;

    float* c1   = ws;                      // 4*S1, later reused as r1
    float* t0   = ws + 4 * S1;             // 3*S0
    float* t1   = ws + 4 * S1 + 3 * S0;    // 3*S1
    float* yA   = ws + 7 * S1 + 3 * S0;    // S1
    float* r1   = ws;                      // S0 == 4*S1, overwrites dead c1

    // 1) level-0 forward DWT: x (16,128,128,64) -> 4x (16,64,64,64)
    fwd_dwt<128><<<16 * 32 * 32 / 4, 256, 0, stream>>>(x, c0LL, c0LH, c0HL, c0HH);

    // 2) level-1 forward DWT: cLL0 -> 4x (16,32,32,64)
    fwd_dwt<64><<<16 * 16 * 16 / 4, 256, 0, stream>>>(c0LL,
        c1 + 0 * S1, c1 + 1 * S1, c1 + 2 * S1, c1 + 3 * S1);

    // 3) local conv level-0 details (Hd=Wd=64)
    local_conv<64, 4><<<dim3(64, 4, 3), 256, 0, stream>>>(
        c0LH, c0HL, c0HH, nullptr,
        wLH0, wHL0, wHH0, nullptr,
        t0 + 0 * S0, t0 + 1 * S0, t0 + 2 * S0, nullptr);

    // 4) local conv level-1 (Hd=Wd=32): LH,HL,HH + LL (yA)
    local_conv<32, 2><<<dim3(32, 4, 4), 256, 0, stream>>>(
        c1 + 1 * S1, c1 + 2 * S1, c1 + 3 * S1, c1 + 0 * S1,
        wLH1, wHL1, wHH1, wLL,
        t1 + 0 * S1, t1 + 1 * S1, t1 + 2 * S1, yA);

    // 5) inverse level-1: (yA, t1) -> r1 (16,64,64,64)
    inv_dwt<64><<<16 * 32 * 32 / 4, 256, 0, stream>>>(
        yA, t1 + 0 * S1, t1 + 1 * S1, t1 + 2 * S1, r1);

    // 6) inverse level-0: (r1, t0) -> out (16,128,128,64)
    inv_dwt<128><<<16 * 64 * 64 / 4, 256, 0, stream>>>(
        r1, t0 + 0 * S0, t0 + 1 * S0, t0 + 2 * S0, out);
}